// Round 1
// baseline (4263.386 us; speedup 1.0000x reference)
//
#include <hip/hip_runtime.h>
#include <hip/hip_bf16.h>

// Collapsed-projector persistent-GRU kernel for MI355X.
// Round 7 = Round 6 base (3.35 ms steady) +
//  (a) per-publisher flags -> single-round gather (tags still sole
//      correctness mechanism; flags are perf-only heuristic),
//  (b) SYSTEM -> AGENT scope on the whole exchange (cross-XCD only
//      needs device scope; coherence point = LLC),
//  (c) gt_*/htmp LDS padded to stride 20 (kills 4-way bank conflicts),
//  (d) round-robin OUT-writer block (removes j==0 straggler).

#define HIDDEN 1024
#define INDIM  63
#define TSEQ   512
#define MB     16
#define NGRP   4
#define HWORDS 512          // 8B words per h row (2 cols each)

typedef __attribute__((ext_vector_type(8))) short bfrag8;  // 8 bf16 in 4 VGPRs
typedef __attribute__((ext_vector_type(4))) float ffrag4;  // MFMA accumulator
typedef unsigned long long ull;

#define MFMA_B16(a, b, c) __builtin_amdgcn_mfma_f32_16x16x32_bf16((a), (b), (c), 0, 0, 0)

__device__ __forceinline__ short f2bf(float x) {
  __hip_bfloat16 b = __float2bfloat16(x);
  return __builtin_bit_cast(short, b);
}
__device__ __forceinline__ float bf2f(short s) {
  unsigned u = ((unsigned)(unsigned short)s) << 16;
  return __builtin_bit_cast(float, u);
}

// ---------------- precompute kernels ----------------

__global__ void k_t1(const float* __restrict__ W2, const float* __restrict__ b1,
                     const float* __restrict__ b2, float* __restrict__ t1) {
  const int w = threadIdx.x >> 6, lane = threadIdx.x & 63;
  const int o = blockIdx.x * 4 + w;
  if (o >= HIDDEN) return;
  const float* row = W2 + (size_t)o * HIDDEN;
  float s = 0.f;
  for (int k = lane; k < HIDDEN; k += 64) s += row[k] * b1[k];
  for (int off = 32; off; off >>= 1) s += __shfl_down(s, off, 64);
  if (lane == 0) t1[o] = s + b2[o];
}

__global__ void k_bp(const float* __restrict__ W3, const float* __restrict__ t1,
                     const float* __restrict__ b3, float* __restrict__ bp) {
  const int w = threadIdx.x >> 6, lane = threadIdx.x & 63;
  for (int d = w; d < INDIM; d += 4) {
    const float* row = W3 + (size_t)d * HIDDEN;
    float s = 0.f;
    for (int k = lane; k < HIDDEN; k += 64) s += row[k] * t1[k];
    for (int off = 32; off; off >>= 1) s += __shfl_down(s, off, 64);
    if (lane == 0) bp[d] = s + b3[d];
  }
}

__global__ void k_gemm(const float* __restrict__ A, const float* __restrict__ B,
                       float* __restrict__ C, int M, int N, int K) {
  __shared__ float As[16][17], Bs[16][17];
  const int tx = threadIdx.x, ty = threadIdx.y;
  const int row = blockIdx.y * 16 + ty;
  const int col = blockIdx.x * 16 + tx;
  float acc = 0.f;
  for (int k0 = 0; k0 < K; k0 += 16) {
    As[ty][tx] = (row < M) ? A[(size_t)row * K + k0 + tx] : 0.f;
    Bs[ty][tx] = B[(size_t)(k0 + ty) * N + col];
    __syncthreads();
#pragma unroll
    for (int kk = 0; kk < 16; ++kk) acc += As[ty][kk] * Bs[kk][tx];
    __syncthreads();
  }
  if (row < M && col < N) C[(size_t)row * N + col] = acc;
}

// ---------------- main persistent kernel ----------------

__global__ __launch_bounds__(256, 1) void k_main(
    const float* __restrict__ X,
    const float* __restrict__ W_ih, const float* __restrict__ W_hh,
    const float* __restrict__ b_ih, const float* __restrict__ b_hh,
    const float* __restrict__ WpF, const float* __restrict__ bpF,
    const int* __restrict__ pCL, const int* __restrict__ pGT,
    ull* __restrict__ hb, int* __restrict__ fl, float* __restrict__ OUT) {
  __shared__ short h_st[MB][HIDDEN + 8];   // staged h, row stride 2064B (uniform 8-group b128, minimal)
  __shared__ short inp_bf[MB][88];
  __shared__ float inp_f[MB][68];
  // stride 20 words: bank = (16q + 20i + c) mod 32 -> uniform 2-way (free)
  __shared__ float gt_z[MB][20], gt_hn[MB][20];
  __shared__ float gt_ir[MB][20], gt_iz[MB][20], gt_in[MB][20];
  __shared__ short htmp[MB][20];           // h-slice repack for packed store

  const int tid = threadIdx.x;
  const int w = tid >> 6;
  const int lane = tid & 63;
  const int c = lane & 15;
  const int quad = lane >> 4;
  const int g = blockIdx.x >> 6;
  const int j = blockIdx.x & 63;

  const int gtv = pGT[0];
  int period = pCL[0] + gtv;
  if (period < 1) period = 1;

  // --- persistent register-resident weight fragments ---
  bfrag8 wB[32];
  bfrag8 wp[32];
  if (w < 3) {
    const float* wr = W_hh + ((size_t)w * HIDDEN + (size_t)j * 16 + c) * HIDDEN;
#pragma unroll
    for (int ks = 0; ks < 32; ++ks) {
      const float* p = wr + ks * 32 + quad * 8;
      bfrag8 f;
#pragma unroll
      for (int e = 0; e < 8; ++e) f[e] = f2bf(p[e]);
      wB[ks] = f;
    }
  } else {
#pragma unroll
    for (int gate = 0; gate < 3; ++gate) {
      const float* wr = W_ih + ((size_t)gate * HIDDEN + (size_t)j * 16 + c) * INDIM;
#pragma unroll
      for (int ks = 0; ks < 2; ++ks) {
        bfrag8 f;
#pragma unroll
        for (int e = 0; e < 8; ++e) {
          int k = ks * 32 + quad * 8 + e;
          f[e] = (k < INDIM) ? f2bf(wr[k]) : (short)0;
        }
        wB[gate * 2 + ks] = f;
      }
    }
  }
  const int dd = 16 * w + c;
  {
    const float* wr = WpF + (size_t)dd * HIDDEN;
#pragma unroll
    for (int ks = 0; ks < 32; ++ks) {
      bfrag8 f;
#pragma unroll
      for (int e = 0; e < 8; ++e)
        f[e] = (dd < INDIM) ? f2bf(wr[ks * 32 + quad * 8 + e]) : (short)0;
      wp[ks] = f;
    }
  }

  float bias_g;
  if (w == 0)      bias_g = b_ih[j * 16 + c] + b_hh[j * 16 + c];
  else if (w == 1) bias_g = b_ih[HIDDEN + j * 16 + c] + b_hh[HIDDEN + j * 16 + c];
  else if (w == 2) bias_g = b_hh[2 * HIDDEN + j * 16 + c];
  else             bias_g = b_ih[2 * HIDDEN + j * 16 + c];
  const float bp_l = (dd < INDIM) ? bpF[dd] : 0.f;

  for (int i = tid; i < MB * (HIDDEN + 8); i += 256) ((short*)h_st)[i] = 0;
  for (int i = tid; i < MB * 88; i += 256) ((short*)inp_bf)[i] = 0;
  for (int i = tid; i < MB * 68; i += 256) ((float*)inp_f)[i] = 0.f;

  // tagged h buffers: [2][NGRP][MB][HWORDS] ull
  ull* hb_g[2] = {hb + (size_t)g * MB * HWORDS,
                  hb + (size_t)(NGRP + g) * MB * HWORDS};
  // per-publisher flags for this group (perf-only; tags carry correctness)
  int* fg = fl + g * 64;
  // each thread's 32 gather words come from exactly two publishers:
  const int fj1 = tid >> 3;        // words (tid & 511) -> publisher tid>>3
  const int fj2 = fj1 + 32;        // words (tid+256) & 511 -> publisher +32

  for (int t = 0; t < TSEQ; ++t) {
    const unsigned tg = (unsigned)(t + 1);
    const bool teach = ((t % period) < gtv);
    if (teach) {
      const int row = tid >> 4, d0 = (tid & 15) * 4;
      const float* xr = X + ((size_t)(g * MB + row) * TSEQ + t) * INDIM;
#pragma unroll
      for (int e = 0; e < 4; ++e) {
        int d = d0 + e;
        float v = (d < INDIM) ? xr[d] : 0.f;
        inp_f[row][d] = v;
        inp_bf[row][d] = f2bf(v);
      }
    }
    __syncthreads();  // S1: inp ready; h_st holds h(t-1)

    ffrag4 ghr;
    float hp[4];  // w0 snapshots h_prev before gather overwrites h_st
    if (w < 3) {
      ffrag4 acc[4];
#pragma unroll
      for (int e = 0; e < 4; ++e) {
        acc[0][e] = bias_g; acc[1][e] = 0.f; acc[2][e] = 0.f; acc[3][e] = 0.f;
      }
#pragma unroll
      for (int ks = 0; ks < 32; ++ks) {
        const bfrag8 a = *(const bfrag8*)&h_st[c][ks * 32 + quad * 8];
        acc[ks & 3] = MFMA_B16(a, wB[ks], acc[ks & 3]);
      }
      ffrag4 gsum = acc[0] + acc[1] + acc[2] + acc[3];
      if (w == 1) {
#pragma unroll
        for (int i = 0; i < 4; ++i) gt_z[quad * 4 + i][c] = gsum[i];
      } else if (w == 2) {
#pragma unroll
        for (int i = 0; i < 4; ++i) gt_hn[quad * 4 + i][c] = gsum[i];
      } else {
        ghr = gsum;
#pragma unroll
        for (int i = 0; i < 4; ++i) hp[i] = bf2f(h_st[quad * 4 + i][j * 16 + c]);
      }
    } else {
      ffrag4 gir, giz, gin;
#pragma unroll
      for (int e = 0; e < 4; ++e) { gir[e] = 0.f; giz[e] = 0.f; gin[e] = bias_g; }
#pragma unroll
      for (int ks = 0; ks < 2; ++ks) {
        const bfrag8 a = *(const bfrag8*)&inp_bf[c][ks * 32 + quad * 8];
        gir = MFMA_B16(a, wB[0 + ks], gir);
        giz = MFMA_B16(a, wB[2 + ks], giz);
        gin = MFMA_B16(a, wB[4 + ks], gin);
      }
#pragma unroll
      for (int i = 0; i < 4; ++i) {
        gt_ir[quad * 4 + i][c] = gir[i];
        gt_iz[quad * 4 + i][c] = giz[i];
        gt_in[quad * 4 + i][c] = gin[i];
      }
    }
    __syncthreads();  // S2: gate tiles ready; h_st now dead until gather refill

    ull* hw = hb_g[t & 1];
    if (w == 0) {
      // gates -> h_new (bf16) -> htmp (wave-local repack) -> tagged publish
#pragma unroll
      for (int i = 0; i < 4; ++i) {
        const int row = quad * 4 + i;
        float r = 1.f / (1.f + __expf(-(ghr[i] + gt_ir[row][c])));
        float z = 1.f / (1.f + __expf(-(gt_z[row][c] + gt_iz[row][c])));
        float n = tanhf(gt_in[row][c] + r * gt_hn[row][c]);
        htmp[row][c] = f2bf((1.f - z) * n + z * hp[i]);
      }
      // TBAA-safe repack: same-typed (short) loads + compiler memory fence so
      // the reads can never be scheduled above the htmp stores.
      asm volatile("" ::: "memory");
      const int r = lane >> 2, q4 = (lane & 3) * 4;   // 4 cols = 2 words per lane
      unsigned lo0 = (unsigned)(unsigned short)htmp[r][q4 + 0] |
                     ((unsigned)(unsigned short)htmp[r][q4 + 1] << 16);
      unsigned lo1 = (unsigned)(unsigned short)htmp[r][q4 + 2] |
                     ((unsigned)(unsigned short)htmp[r][q4 + 3] << 16);
      ull w0v = ((ull)tg << 32) | lo0;
      ull w1v = ((ull)tg << 32) | lo1;
      ull* dst = hw + (size_t)r * HWORDS + 8 * j + (lane & 3) * 2;
      __hip_atomic_store(dst, w0v, __ATOMIC_RELAXED, __HIP_MEMORY_SCOPE_AGENT);
      __hip_atomic_store(dst + 1, w1v, __ATOMIC_RELAXED, __HIP_MEMORY_SCOPE_AGENT);
      // drain payload to the coherence point, then raise this block's flag.
      asm volatile("s_waitcnt vmcnt(0)" ::: "memory");
      if (lane == 0)
        __hip_atomic_store(&fg[j], (int)tg, __ATOMIC_RELAXED,
                           __HIP_MEMORY_SCOPE_AGENT);
    }

    // gather h(t): spin on the two needed publisher flags (cheap hot lines),
    // then ONE payload round; tag-retry remains as the correctness backstop.
    {
      while (__hip_atomic_load(&fg[fj1], __ATOMIC_RELAXED,
                               __HIP_MEMORY_SCOPE_AGENT) < (int)tg)
        __builtin_amdgcn_s_sleep(1);
      while (__hip_atomic_load(&fg[fj2], __ATOMIC_RELAXED,
                               __HIP_MEMORY_SCOPE_AGENT) < (int)tg)
        __builtin_amdgcn_s_sleep(1);

      ull v[32];
#pragma unroll
      for (int s = 0; s < 32; ++s)
        v[s] = __hip_atomic_load(&hw[tid + s * 256], __ATOMIC_RELAXED,
                                 __HIP_MEMORY_SCOPE_AGENT);
      bool bad = true;
      while (bad) {
        bad = false;
#pragma unroll
        for (int s = 0; s < 32; ++s) {
          if ((unsigned)(v[s] >> 32) != tg) {
            v[s] = __hip_atomic_load(&hw[tid + s * 256], __ATOMIC_RELAXED,
                                     __HIP_MEMORY_SCOPE_AGENT);
            bad = true;
          }
        }
      }
#pragma unroll
      for (int s = 0; s < 32; ++s) {
        const int widx = tid + s * 256;          // 16 rows x 512 words
        *(unsigned*)&h_st[widx >> 9][(widx & 511) * 2] = (unsigned)v[s];
      }
    }
    __syncthreads();  // S3: h_st = h(t)

    // out(t) = inp(t) + h(t) @ Wp^T + bp
    // round-robin the OUT-writer so no single block is a systematic straggler
    const int wj = t & 63;
    const bool rep = (t + 1 < TSEQ) && !(((t + 1) % period) < gtv);
    if (rep || j == wj) {
      ffrag4 oa0, oa1;
#pragma unroll
      for (int e = 0; e < 4; ++e) { oa0[e] = bp_l; oa1[e] = 0.f; }
#pragma unroll
      for (int ks = 0; ks < 32; ++ks) {
        const bfrag8 a = *(const bfrag8*)&h_st[c][ks * 32 + quad * 8];
        if (ks & 1) oa1 = MFMA_B16(a, wp[ks], oa1);
        else        oa0 = MFMA_B16(a, wp[ks], oa0);
      }
      ffrag4 o = oa0 + oa1;
#pragma unroll
      for (int i = 0; i < 4; ++i) {
        const int row = quad * 4 + i;
        if (dd < INDIM) {
          float val = o[i] + inp_f[row][dd];
          if (j == wj) OUT[((size_t)(g * MB + row) * TSEQ + t) * INDIM + dd] = val;
          if (rep) { inp_f[row][dd] = val; inp_bf[row][dd] = f2bf(val); }
        } else if (rep) {
          inp_bf[row][dd] = 0;
        }
      }
    }
    // loop-head S1 orders inp writes vs next gi reads
  }
}

// ---------------- host ----------------

extern "C" void kernel_launch(void* const* d_in, const int* in_sizes, int n_in,
                              void* d_out, int out_size, void* d_ws, size_t ws_size,
                              hipStream_t stream) {
  const float* X    = (const float*)d_in[0];
  const float* W_ih = (const float*)d_in[1];
  const float* W_hh = (const float*)d_in[2];
  const float* b_ih = (const float*)d_in[3];
  const float* b_hh = (const float*)d_in[4];
  const float* W1   = (const float*)d_in[5];
  const float* b1   = (const float*)d_in[6];
  const float* W2   = (const float*)d_in[7];
  const float* b2   = (const float*)d_in[8];
  const float* W3   = (const float*)d_in[9];
  const float* b3   = (const float*)d_in[10];
  const int* pCL    = (const int*)d_in[11];
  const int* pGT    = (const int*)d_in[12];
  float* OUT = (float*)d_out;

  // layout: T2 aliases hb (dead before k_main; hb+flags memset after)
  char* ws = (char*)d_ws;
  float* bp = (float*)(ws + 1024);        // 63 f32
  float* t1 = (float*)(ws + 2048);        // 1024 f32
  float* Wp = (float*)(ws + 8192);        // 63x1024 f32 (258048 B)
  float* T2 = (float*)(ws + 270336);      // 63x1024 f32 scratch (aliases hb)
  ull*   hb = (ull*)(ws + 270336);        // 2 x 4 x 16 x 512 ull = 512 KB
  int*   fl = (int*)(ws + 270336 + 2 * NGRP * MB * HWORDS * sizeof(ull)); // 4x64 int
  if (ws_size < 795 * 1024) return;

  k_t1<<<256, 256, 0, stream>>>(W2, b1, b2, t1);
  k_gemm<<<dim3(64, 4), dim3(16, 16), 0, stream>>>(W3, W2, T2, INDIM, HIDDEN, HIDDEN);
  k_gemm<<<dim3(64, 4), dim3(16, 16), 0, stream>>>(T2, W1, Wp, INDIM, HIDDEN, HIDDEN);
  k_bp<<<1, 256, 0, stream>>>(W3, t1, b3, bp);
  hipMemsetAsync(hb, 0,
                 2 * NGRP * MB * HWORDS * sizeof(ull) + NGRP * 64 * sizeof(int),
                 stream);  // tags := 0, flags := 0
  k_main<<<256, 256, 0, stream>>>(X, W_ih, W_hh, b_ih, b_hh, Wp, bp, pCL, pGT,
                                  hb, fl, OUT);
}

// Round 2
// 3354.473 us; speedup vs baseline: 1.2710x; 1.2710x over previous
//
#include <hip/hip_runtime.h>
#include <hip/hip_bf16.h>

// Collapsed-projector persistent-GRU kernel for MI355X.
// Round 8 = Round 6 proven exchange (LDS pub_flag issue-gate, SYSTEM scope,
// optimistic gather + tag retry; 3.35 ms) +
//  (a) self-consistent 4B tagged words ((tag16<<16)|bf16): tag+payload share
//      one dword -> dword atomicity makes ANY load width safe. Gather is now
//      16 x global_load_dwordx4 sc0 sc1 per thread (16B coherent) instead of
//      32 x 8B atomic loads: half the LLC request count, same bytes.
//  (b) X(t+1) prefetched into registers during the exchange shadow.
//  (c) kept from R7: gt_* stride-20 pads, round-robin OUT-writer.

#define HIDDEN 1024
#define INDIM  63
#define TSEQ   512
#define MB     16
#define NGRP   4
#define HB_DW  (MB * 1024)   // dwords per (parity, group) buffer = 64 KB

typedef __attribute__((ext_vector_type(8))) short bfrag8;  // 8 bf16 in 4 VGPRs
typedef __attribute__((ext_vector_type(4))) float ffrag4;  // MFMA accumulator
typedef __attribute__((ext_vector_type(4))) unsigned u32x4;
typedef unsigned long long ull;

#define MFMA_B16(a, b, c) __builtin_amdgcn_mfma_f32_16x16x32_bf16((a), (b), (c), 0, 0, 0)

// coherent 16B load (bypass L1/L2 -> LLC), rule-18 fencing done at call site
#define GLOAD4(dst, ptr) \
  asm volatile("global_load_dwordx4 %0, %1, off sc0 sc1" \
               : "=v"(dst) : "v"(ptr) : "memory")

__device__ __forceinline__ short f2bf(float x) {
  __hip_bfloat16 b = __float2bfloat16(x);
  return __builtin_bit_cast(short, b);
}
__device__ __forceinline__ float bf2f(short s) {
  unsigned u = ((unsigned)(unsigned short)s) << 16;
  return __builtin_bit_cast(float, u);
}

// ---------------- precompute kernels ----------------

__global__ void k_t1(const float* __restrict__ W2, const float* __restrict__ b1,
                     const float* __restrict__ b2, float* __restrict__ t1) {
  const int w = threadIdx.x >> 6, lane = threadIdx.x & 63;
  const int o = blockIdx.x * 4 + w;
  if (o >= HIDDEN) return;
  const float* row = W2 + (size_t)o * HIDDEN;
  float s = 0.f;
  for (int k = lane; k < HIDDEN; k += 64) s += row[k] * b1[k];
  for (int off = 32; off; off >>= 1) s += __shfl_down(s, off, 64);
  if (lane == 0) t1[o] = s + b2[o];
}

__global__ void k_bp(const float* __restrict__ W3, const float* __restrict__ t1,
                     const float* __restrict__ b3, float* __restrict__ bp) {
  const int w = threadIdx.x >> 6, lane = threadIdx.x & 63;
  for (int d = w; d < INDIM; d += 4) {
    const float* row = W3 + (size_t)d * HIDDEN;
    float s = 0.f;
    for (int k = lane; k < HIDDEN; k += 64) s += row[k] * t1[k];
    for (int off = 32; off; off >>= 1) s += __shfl_down(s, off, 64);
    if (lane == 0) bp[d] = s + b3[d];
  }
}

__global__ void k_gemm(const float* __restrict__ A, const float* __restrict__ B,
                       float* __restrict__ C, int M, int N, int K) {
  __shared__ float As[16][17], Bs[16][17];
  const int tx = threadIdx.x, ty = threadIdx.y;
  const int row = blockIdx.y * 16 + ty;
  const int col = blockIdx.x * 16 + tx;
  float acc = 0.f;
  for (int k0 = 0; k0 < K; k0 += 16) {
    As[ty][tx] = (row < M) ? A[(size_t)row * K + k0 + tx] : 0.f;
    Bs[ty][tx] = B[(size_t)(k0 + ty) * N + col];
    __syncthreads();
#pragma unroll
    for (int kk = 0; kk < 16; ++kk) acc += As[ty][kk] * Bs[kk][tx];
    __syncthreads();
  }
  if (row < M && col < N) C[(size_t)row * N + col] = acc;
}

// ---------------- main persistent kernel ----------------

__global__ __launch_bounds__(256, 1) void k_main(
    const float* __restrict__ X,
    const float* __restrict__ W_ih, const float* __restrict__ W_hh,
    const float* __restrict__ b_ih, const float* __restrict__ b_hh,
    const float* __restrict__ WpF, const float* __restrict__ bpF,
    const int* __restrict__ pCL, const int* __restrict__ pGT,
    unsigned* __restrict__ hb, float* __restrict__ OUT) {
  __shared__ short h_st[MB][HIDDEN + 8];   // staged h, row stride 2064B
  __shared__ short inp_bf[MB][88];
  __shared__ float inp_f[MB][68];
  // stride 20 words: bank = (16q + 20i + c) mod 32 -> uniform 2-way (free)
  __shared__ float gt_z[MB][20], gt_hn[MB][20];
  __shared__ float gt_ir[MB][20], gt_iz[MB][20], gt_in[MB][20];
  __shared__ short htmp[MB][20];           // h-slice repack for packed store
  __shared__ int pub_flag;                 // publish-issue gate (perf only)

  const int tid = threadIdx.x;
  const int w = tid >> 6;
  const int lane = tid & 63;
  const int c = lane & 15;
  const int quad = lane >> 4;
  const int g = blockIdx.x >> 6;
  const int j = blockIdx.x & 63;

  const int gtv = pGT[0];
  int period = pCL[0] + gtv;
  if (period < 1) period = 1;

  // --- persistent register-resident weight fragments ---
  bfrag8 wB[32];
  bfrag8 wp[32];
  if (w < 3) {
    const float* wr = W_hh + ((size_t)w * HIDDEN + (size_t)j * 16 + c) * HIDDEN;
#pragma unroll
    for (int ks = 0; ks < 32; ++ks) {
      const float* p = wr + ks * 32 + quad * 8;
      bfrag8 f;
#pragma unroll
      for (int e = 0; e < 8; ++e) f[e] = f2bf(p[e]);
      wB[ks] = f;
    }
  } else {
#pragma unroll
    for (int gate = 0; gate < 3; ++gate) {
      const float* wr = W_ih + ((size_t)gate * HIDDEN + (size_t)j * 16 + c) * INDIM;
#pragma unroll
      for (int ks = 0; ks < 2; ++ks) {
        bfrag8 f;
#pragma unroll
        for (int e = 0; e < 8; ++e) {
          int k = ks * 32 + quad * 8 + e;
          f[e] = (k < INDIM) ? f2bf(wr[k]) : (short)0;
        }
        wB[gate * 2 + ks] = f;
      }
    }
  }
  const int dd = 16 * w + c;
  {
    const float* wr = WpF + (size_t)dd * HIDDEN;
#pragma unroll
    for (int ks = 0; ks < 32; ++ks) {
      bfrag8 f;
#pragma unroll
      for (int e = 0; e < 8; ++e)
        f[e] = (dd < INDIM) ? f2bf(wr[ks * 32 + quad * 8 + e]) : (short)0;
      wp[ks] = f;
    }
  }

  float bias_g;
  if (w == 0)      bias_g = b_ih[j * 16 + c] + b_hh[j * 16 + c];
  else if (w == 1) bias_g = b_ih[HIDDEN + j * 16 + c] + b_hh[HIDDEN + j * 16 + c];
  else if (w == 2) bias_g = b_hh[2 * HIDDEN + j * 16 + c];
  else             bias_g = b_ih[2 * HIDDEN + j * 16 + c];
  const float bp_l = (dd < INDIM) ? bpF[dd] : 0.f;

  for (int i = tid; i < MB * (HIDDEN + 8); i += 256) ((short*)h_st)[i] = 0;
  for (int i = tid; i < MB * 88; i += 256) ((short*)inp_bf)[i] = 0;
  for (int i = tid; i < MB * 68; i += 256) ((float*)inp_f)[i] = 0.f;
  if (tid == 0) pub_flag = 0;

  // tagged h buffers: [2][NGRP][MB][1024] dwords, dword = (tag16<<16)|bf16
  unsigned* hb_g[2] = {hb + (size_t)g * HB_DW,
                       hb + (size_t)(NGRP + g) * HB_DW};

  // X prefetch (teacher-forcing rows) held in registers across iterations
  const int xrow = tid >> 4, xd0 = (tid & 15) * 4;
  float xp[4];
  if ((0 % period) < gtv) {
    const float* xr = X + ((size_t)(g * MB + xrow) * TSEQ + 0) * INDIM;
#pragma unroll
    for (int e = 0; e < 4; ++e) xp[e] = (xd0 + e < INDIM) ? xr[xd0 + e] : 0.f;
  }

  for (int t = 0; t < TSEQ; ++t) {
    const unsigned tg = (unsigned)(t + 1);
    const bool teach = ((t % period) < gtv);
    if (teach) {
      // stores of the register-prefetched X row (loaded last iteration)
#pragma unroll
      for (int e = 0; e < 4; ++e) {
        inp_f[xrow][xd0 + e] = xp[e];
        inp_bf[xrow][xd0 + e] = f2bf(xp[e]);
      }
    }
    __syncthreads();  // S1: inp ready; h_st holds h(t-1)

    ffrag4 ghr;
    float hp[4];  // w0 snapshots h_prev before gather overwrites h_st
    if (w < 3) {
      ffrag4 acc[4];
#pragma unroll
      for (int e = 0; e < 4; ++e) {
        acc[0][e] = bias_g; acc[1][e] = 0.f; acc[2][e] = 0.f; acc[3][e] = 0.f;
      }
#pragma unroll
      for (int ks = 0; ks < 32; ++ks) {
        const bfrag8 a = *(const bfrag8*)&h_st[c][ks * 32 + quad * 8];
        acc[ks & 3] = MFMA_B16(a, wB[ks], acc[ks & 3]);
      }
      ffrag4 gsum = acc[0] + acc[1] + acc[2] + acc[3];
      if (w == 1) {
#pragma unroll
        for (int i = 0; i < 4; ++i) gt_z[quad * 4 + i][c] = gsum[i];
      } else if (w == 2) {
#pragma unroll
        for (int i = 0; i < 4; ++i) gt_hn[quad * 4 + i][c] = gsum[i];
      } else {
        ghr = gsum;
#pragma unroll
        for (int i = 0; i < 4; ++i) hp[i] = bf2f(h_st[quad * 4 + i][j * 16 + c]);
      }
    } else {
      ffrag4 gir, giz, gin;
#pragma unroll
      for (int e = 0; e < 4; ++e) { gir[e] = 0.f; giz[e] = 0.f; gin[e] = bias_g; }
#pragma unroll
      for (int ks = 0; ks < 2; ++ks) {
        const bfrag8 a = *(const bfrag8*)&inp_bf[c][ks * 32 + quad * 8];
        gir = MFMA_B16(a, wB[0 + ks], gir);
        giz = MFMA_B16(a, wB[2 + ks], giz);
        gin = MFMA_B16(a, wB[4 + ks], gin);
      }
#pragma unroll
      for (int i = 0; i < 4; ++i) {
        gt_ir[quad * 4 + i][c] = gir[i];
        gt_iz[quad * 4 + i][c] = giz[i];
        gt_in[quad * 4 + i][c] = gin[i];
      }
    }
    __syncthreads();  // S2: gate tiles ready; h_st now dead until gather refill

    unsigned* hw = hb_g[t & 1];
    if (w == 0) {
      // gates -> h_new (bf16) -> htmp (wave-local repack) -> tagged publish
#pragma unroll
      for (int i = 0; i < 4; ++i) {
        const int row = quad * 4 + i;
        float r = 1.f / (1.f + __expf(-(ghr[i] + gt_ir[row][c])));
        float z = 1.f / (1.f + __expf(-(gt_z[row][c] + gt_iz[row][c])));
        float n = tanhf(gt_in[row][c] + r * gt_hn[row][c]);
        htmp[row][c] = f2bf((1.f - z) * n + z * hp[i]);
      }
      // TBAA-safe repack: same-typed (short) loads + compiler memory fence so
      // the reads can never be scheduled above the htmp stores.
      asm volatile("" ::: "memory");
      const int r = lane >> 2, q4 = (lane & 3) * 4;   // 4 cols = 4 dwords per lane
      unsigned d0 = ((unsigned)tg << 16) | (unsigned)(unsigned short)htmp[r][q4 + 0];
      unsigned d1 = ((unsigned)tg << 16) | (unsigned)(unsigned short)htmp[r][q4 + 1];
      unsigned d2 = ((unsigned)tg << 16) | (unsigned)(unsigned short)htmp[r][q4 + 2];
      unsigned d3 = ((unsigned)tg << 16) | (unsigned)(unsigned short)htmp[r][q4 + 3];
      ull w0v = ((ull)d1 << 32) | d0;
      ull w1v = ((ull)d3 << 32) | d2;
      ull* dst = (ull*)(hw + (size_t)r * 1024 + 16 * j + q4);
      __hip_atomic_store(dst, w0v, __ATOMIC_RELAXED, __HIP_MEMORY_SCOPE_SYSTEM);
      __hip_atomic_store(dst + 1, w1v, __ATOMIC_RELAXED, __HIP_MEMORY_SCOPE_SYSTEM);
      // open the gather gate AFTER the publish stores are issued (no drain).
      asm volatile("" ::: "memory");
      if (lane == 0) *(volatile int*)&pub_flag = (int)tg;
    } else {
      // perf-only gate: wait until w0 has issued its publish (LDS spin,
      // no fabric traffic). Correctness is still carried by the tags.
      while (*(volatile int*)&pub_flag < (int)tg) __builtin_amdgcn_s_sleep(1);
    }

    // issue next-teach-step X loads into registers: they fly during the
    // gather's retry window and are consumed at the next loop head.
    {
      const int tn = t + 1;
      if (tn < TSEQ && ((tn % period) < gtv)) {
        const float* xr = X + ((size_t)(g * MB + xrow) * TSEQ + tn) * INDIM;
#pragma unroll
        for (int e = 0; e < 4; ++e) xp[e] = (xd0 + e < INDIM) ? xr[xd0 + e] : 0.f;
      }
    }

    // gather h(t): the load IS the barrier — retry 16B chunks until all
    // tags == t+1. Each dword is (tag16|bf16): self-consistent at any width.
    {
      u32x4 v[16];
      const unsigned* gp = hw + (size_t)tid * 4;
#pragma unroll
      for (int s = 0; s < 16; ++s) GLOAD4(v[s], gp + s * 1024);
      asm volatile("s_waitcnt vmcnt(0)" ::: "memory");
      __builtin_amdgcn_sched_barrier(0);

      unsigned bad = 0;
#pragma unroll
      for (int s = 0; s < 16; ++s) {
        if ((v[s][0] >> 16) != tg || (v[s][1] >> 16) != tg ||
            (v[s][2] >> 16) != tg || (v[s][3] >> 16) != tg)
          bad |= (1u << s);
      }
      while (__ballot(bad != 0)) {
        // uniform per-chunk reload: lanes whose chunk is already good reload
        // harmlessly (tagged words are write-once per step per parity buffer)
#pragma unroll
        for (int s = 0; s < 16; ++s) {
          if (__ballot((bad >> s) & 1u)) GLOAD4(v[s], gp + s * 1024);
        }
        asm volatile("s_waitcnt vmcnt(0)" ::: "memory");
        __builtin_amdgcn_sched_barrier(0);
        bad = 0;
#pragma unroll
        for (int s = 0; s < 16; ++s) {
          if ((v[s][0] >> 16) != tg || (v[s][1] >> 16) != tg ||
              (v[s][2] >> 16) != tg || (v[s][3] >> 16) != tg)
            bad |= (1u << s);
        }
      }
#pragma unroll
      for (int s = 0; s < 16; ++s) {
        const int ci = tid + s * 256;          // chunk = 4 cols of one row
        const int row = ci >> 8;
        const int cb = (ci & 255) * 4;
        ull p = (ull)(v[s][0] & 0xFFFFu) | ((ull)(v[s][1] & 0xFFFFu) << 16) |
                ((ull)(v[s][2] & 0xFFFFu) << 32) | ((ull)(v[s][3] & 0xFFFFu) << 48);
        *(ull*)&h_st[row][cb] = p;
      }
    }
    __syncthreads();  // S3: h_st = h(t)

    // out(t) = inp(t) + h(t) @ Wp^T + bp
    // round-robin the OUT-writer so no single block is a systematic straggler
    const int wj = t & 63;
    const bool rep = (t + 1 < TSEQ) && !(((t + 1) % period) < gtv);
    if (rep || j == wj) {
      ffrag4 oa0, oa1;
#pragma unroll
      for (int e = 0; e < 4; ++e) { oa0[e] = bp_l; oa1[e] = 0.f; }
#pragma unroll
      for (int ks = 0; ks < 32; ++ks) {
        const bfrag8 a = *(const bfrag8*)&h_st[c][ks * 32 + quad * 8];
        if (ks & 1) oa1 = MFMA_B16(a, wp[ks], oa1);
        else        oa0 = MFMA_B16(a, wp[ks], oa0);
      }
      ffrag4 o = oa0 + oa1;
#pragma unroll
      for (int i = 0; i < 4; ++i) {
        const int row = quad * 4 + i;
        if (dd < INDIM) {
          float val = o[i] + inp_f[row][dd];
          if (j == wj) OUT[((size_t)(g * MB + row) * TSEQ + t) * INDIM + dd] = val;
          if (rep) { inp_f[row][dd] = val; inp_bf[row][dd] = f2bf(val); }
        } else if (rep) {
          inp_bf[row][dd] = 0;
        }
      }
    }
    // loop-head S1 orders inp writes vs next gi reads
  }
}

// ---------------- host ----------------

extern "C" void kernel_launch(void* const* d_in, const int* in_sizes, int n_in,
                              void* d_out, int out_size, void* d_ws, size_t ws_size,
                              hipStream_t stream) {
  const float* X    = (const float*)d_in[0];
  const float* W_ih = (const float*)d_in[1];
  const float* W_hh = (const float*)d_in[2];
  const float* b_ih = (const float*)d_in[3];
  const float* b_hh = (const float*)d_in[4];
  const float* W1   = (const float*)d_in[5];
  const float* b1   = (const float*)d_in[6];
  const float* W2   = (const float*)d_in[7];
  const float* b2   = (const float*)d_in[8];
  const float* W3   = (const float*)d_in[9];
  const float* b3   = (const float*)d_in[10];
  const int* pCL    = (const int*)d_in[11];
  const int* pGT    = (const int*)d_in[12];
  float* OUT = (float*)d_out;

  // layout: T2 aliases hb (dead before k_main; hb memset after)
  char* ws = (char*)d_ws;
  float* bp = (float*)(ws + 1024);        // 63 f32
  float* t1 = (float*)(ws + 2048);        // 1024 f32
  float* Wp = (float*)(ws + 8192);        // 63x1024 f32 (258048 B)
  float* T2 = (float*)(ws + 270336);      // 63x1024 f32 scratch (aliases hb)
  unsigned* hb = (unsigned*)(ws + 270336); // 2 x 4 x 16 x 1024 dwords = 512 KB
  if (ws_size < 795 * 1024) return;

  k_t1<<<256, 256, 0, stream>>>(W2, b1, b2, t1);
  k_gemm<<<dim3(64, 4), dim3(16, 16), 0, stream>>>(W3, W2, T2, INDIM, HIDDEN, HIDDEN);
  k_gemm<<<dim3(64, 4), dim3(16, 16), 0, stream>>>(T2, W1, Wp, INDIM, HIDDEN, HIDDEN);
  k_bp<<<1, 256, 0, stream>>>(W3, t1, b3, bp);
  hipMemsetAsync(hb, 0, (size_t)2 * NGRP * HB_DW * sizeof(unsigned), stream);  // tags := 0
  k_main<<<256, 256, 0, stream>>>(X, W_ih, W_hh, b_ih, b_hh, Wp, bp, pCL, pGT, hb, OUT);
}